// Round 6
// baseline (325.504 us; speedup 1.0000x reference)
//
#include <hip/hip_runtime.h>

// CharAttention round-6: INSTRUMENTATION + surgical pass.
// Five rounds of counter-blind modeling under-predict the ~85us kernel 2-6x;
// the kernel has been invisible below the ~119us harness fills since R2.
// This round: repeat the compute phases (rk->scores->y->out) NREP=2 times
// (idempotent: all LDS state re-derived identically; asm fences block CSE).
// Staging runs once. The kernel surfaces in top-5 WITH its own counters, and
// the scaling factor discriminates throughput-bound (T~2x) vs latency-bound
// (T~1.3x) for round 7. Surgical single-pass improvements folded in:
//  - static zero-filled stage (6 writes) -> enables static unrolled y-loop
//    (the old dynamic loop exposed LDS latency per iteration)
//  - ps preloaded via 6 b128 broadcast reads into regs before the y fmafs
//  - max-free softmax + deferred normalization (validated in R5, absmax ok)
//  - xq via s_load (SMEM pipe) issued before staging so latency overlaps
// One problem per wave, 4 waves/block, grid 16384, 15.75KB LDS, VGPR-light.

#define CB      24
#define CC      32
#define DD      16
#define THREEC  96
#define NBW     (512 * 128)
#define WPB     4
#define XSS     34              // xs row stride: even (8B-aligned), <=2-way banks
#define NREP    2               // instrumentation repeat; set 1 after diagnosis

__device__ __align__(16) float4 g_M4[2][8][CC];  // [h][e4][c] = Mt[h][c][4e4..]
__device__ __align__(16) float4 g_P4[2][8][CC];  // [h][e4][c] = Pt[h][c][4e4..]

__global__ void precompute_mp(const float* __restrict__ w_attn,
                              const float* __restrict__ w_proj)
{
    const int idx = blockIdx.x * 256 + threadIdx.x;   // 512 entries
    const int h = idx >> 8, e4 = (idx >> 5) & 7, c = idx & 31;
    float m[4], p[4];
    #pragma unroll
    for (int k = 0; k < 4; ++k) {
        const int e = 4 * e4 + k;
        float mm = 0.f, pp = 0.f;
        #pragma unroll
        for (int d = 0; d < DD; ++d) {
            const int i = DD * h + d;
            mm = fmaf(w_attn[e * THREEC + i],          w_attn[c * THREEC + CC + i], mm);
            pp = fmaf(w_attn[e * THREEC + 2 * CC + i], w_proj[i * CC + c],          pp);
        }
        m[k] = 0.25f * mm;                        // fold 1/sqrt(D)
        p[k] = pp;
    }
    g_M4[h][e4][c] = make_float4(m[0], m[1], m[2], m[3]);
    g_P4[h][e4][c] = make_float4(p[0], p[1], p[2], p[3]);
}

struct __align__(16) WaveSmem {
    float xs[CB][XSS];          // staged x rows, zero-filled past L (3264 B)
    float rks[2][CC];           // rk per head (base 3264, 16B-aligned)
    float ps[2][CC];            // UNNORMALIZED exp(score); masked slots 0 (3520)
    float ys[2][CC];            // normalized p @ x per head (3776)
};                              // 4032 B -> 4 waves = 15.75 KB/block

__device__ __forceinline__ void wave_fence() {
    __asm__ volatile("s_waitcnt lgkmcnt(0)" ::: "memory");
}

__global__ __launch_bounds__(256, 8) void char_attn_kernel(
    const float* __restrict__ x,        // [B*W, 24, 32]
    const int*   __restrict__ xend,     // [B*W]
    float*       __restrict__ out)      // [B*W, 32]
{
    __shared__ WaveSmem sm[WPB];

    const int tid  = threadIdx.x;
    const int lane = tid & 63;
    const int wave = tid >> 6;
    WaveSmem& S = sm[wave];

    const int i32  = lane & 31;
    const int half = lane >> 5;

    const int sbid = __builtin_amdgcn_readfirstlane(blockIdx.x * WPB + wave);
    const int sq   = __builtin_amdgcn_readfirstlane(xend[sbid]);
    const int L    = sq + 1;

    const float* __restrict__ xb = x + (size_t)sbid * (CB * CC);
    const float* __restrict__ xq = xb + sq * CC;    // scalar address -> s_load

    // xq via SMEM pipe, issued first so latency overlaps the staging below
    float4 xqv[8];
    #pragma unroll
    for (int e = 0; e < 8; ++e) xqv[e] = *(const float4*)(xq + 4 * e);

    // ---- stage x rows; zero-fill past L (static 6-instr loop) ----
    {
        const float2* xb2 = (const float2*)xb;
        const int n2 = L * (CC / 2);            // <= 384
        #pragma unroll
        for (int i = 0; i < 6; ++i) {
            const int t = lane + 64 * i;        // t < 384 always
            float2 v = make_float2(0.f, 0.f);
            if (t < n2) v = xb2[t];             // predicated coalesced load
            const int r = t >> 4, c = (t & 15) * 2;
            *(float2*)&S.xs[r][c] = v;          // 8B-aligned (XSS even)
        }
    }
    wave_fence();                               // xs visible in-wave

    // ======== instrumentation: repeat compute phases NREP times ========
    #pragma unroll 1
    for (int rep = 0; rep < NREP; ++rep) {

        // ---- rk: lane=(c=i32,h=half): rks[h][c] = xq . Mt[h][c][:] ----
        {
            float a0 = 0.f, a1 = 0.f, a2 = 0.f, a3 = 0.f;
            #pragma unroll
            for (int e4 = 0; e4 < 8; ++e4) {
                const float4 mv = g_M4[half][e4][i32];  // coalesced, L1-hot
                a0 = fmaf(mv.x, xqv[e4].x, a0);
                a1 = fmaf(mv.y, xqv[e4].y, a1);
                a2 = fmaf(mv.z, xqv[e4].z, a2);
                a3 = fmaf(mv.w, xqv[e4].w, a3);
            }
            S.rks[half][i32] = (a0 + a1) + (a2 + a3);
        }
        wave_fence();                           // rks visible

        // ---- scores + exp (no max-subtract; s ~ N(0,1)) ----
        float rsum;
        {
            float e = 0.f;
            {
                const float4* rk4 = (const float4*)&S.rks[half][0]; // b128 bcast
                float a0 = 0.f, a1 = 0.f, a2 = 0.f, a3 = 0.f;
                #pragma unroll
                for (int e4 = 0; e4 < 8; ++e4) {
                    const float4 rv = rk4[e4];
                    const float2 x0 = *(const float2*)&S.xs[i32][e4 * 4];
                    const float2 x1 = *(const float2*)&S.xs[i32][e4 * 4 + 2];
                    a0 = fmaf(rv.x, x0.x, a0);
                    a1 = fmaf(rv.y, x0.y, a1);
                    a2 = fmaf(rv.z, x1.x, a2);
                    a3 = fmaf(rv.w, x1.y, a3);
                }
                e = (i32 <= sq) ? __expf((a0 + a1) + (a2 + a3)) : 0.f;
            }
            S.ps[half][i32] = e;                // unnormalized; 0 for masked j
            float sum = e;
            #pragma unroll
            for (int off = 16; off >= 1; off >>= 1)
                sum += __shfl_xor(sum, off);
            rsum = __fdividef(1.f, sum);
        }
        wave_fence();                           // ps visible

        // ---- y: static 24-unroll; ps preloaded via 6 b128 broadcasts ----
        {
            float4 pr[6];
            const float4* ps4 = (const float4*)&S.ps[half][0];
            #pragma unroll
            for (int i = 0; i < 6; ++i) pr[i] = ps4[i];     // covers ps[0..23]
            const float* pf = (const float*)&pr[0];
            float a0 = 0.f, a1 = 0.f;
            #pragma unroll
            for (int j = 0; j < CB; j += 2) {
                a0 = fmaf(pf[j],     S.xs[j][i32],     a0); // b32 conflict-free
                a1 = fmaf(pf[j + 1], S.xs[j + 1][i32], a1);
            }
            S.ys[half][i32] = (a0 + a1) * rsum;
        }
        wave_fence();                           // ys visible

        // ---- out[c] = sum_h ys[h] . Pt[h][c][:] + residual ----
        {
            const float4* y4 = (const float4*)&S.ys[half][0];   // b128 bcast
            float a0 = 0.f, a1 = 0.f, a2 = 0.f, a3 = 0.f;
            #pragma unroll
            for (int e4 = 0; e4 < 8; ++e4) {
                const float4 pv = g_P4[half][e4][i32];          // coalesced, L1-hot
                const float4 yv = y4[e4];
                a0 = fmaf(pv.x, yv.x, a0);
                a1 = fmaf(pv.y, yv.y, a1);
                a2 = fmaf(pv.z, yv.z, a2);
                a3 = fmaf(pv.w, yv.w, a3);
            }
            float t = (a0 + a1) + (a2 + a3);
            t += __shfl_xor(t, 32);             // combine the two heads
            if (lane < CC)
                out[(size_t)sbid * CC + i32] = t + S.xs[sq][i32];
        }
        // no fence needed at loop seam: next phase writes rks only, and the
        // scores-fence of the next rep drains all outstanding DS ops.
    }
}

extern "C" void kernel_launch(void* const* d_in, const int* in_sizes, int n_in,
                              void* d_out, int out_size, void* d_ws, size_t ws_size,
                              hipStream_t stream) {
    const float* x      = (const float*)d_in[0];
    const int*   xend   = (const int*)d_in[1];
    const float* w_attn = (const float*)d_in[2];
    const float* w_proj = (const float*)d_in[3];
    float* out = (float*)d_out;

    precompute_mp<<<dim3(2), dim3(256), 0, stream>>>(w_attn, w_proj);
    char_attn_kernel<<<dim3(NBW / WPB), dim3(WPB * 64), 0, stream>>>(
        x, xend, out);
}

// Round 7
// 303.231 us; speedup vs baseline: 1.0735x; 1.0735x over previous
//
#include <hip/hip_runtime.h>

// CharAttention round-7: NREP diagnosis (R6): hot compute pass = 30us
// (DS-pipe-limited, ~74 DS-ops/problem), first-pass-only costs = ~55us
// (launch of 16384 tiny blocks + x first-touch + scalar-load latency).
// This round attacks the 55us at FULL occupancy (R5 retried at 16 waves/CU
// with fat register state and was neutral):
//  - NPW=4 problems/wave, grid 4096 blocks, 32 waves/CU (launch_bounds(256,8)
//    caps VGPR at 64; register state kept lean: 12 VGPR prefetch, xq in SGPRs)
//  - x of problem k+1 prefetched (3 float4/lane) under problem k's compute
//    chain (~2k cy >= 900 cy HBM latency); stage = cndmask-zero + 6 ds_write
//  - xq s_loads pipelined one problem ahead (SMEM latency off the path)
//  - xend pipelined two ahead
//  - rk hoisted before the stage fence (3 fences/problem, as in best-R3)
//  - staging VMEM halved: 3 global_load_dwordx4 instead of 6 dwordx2
//  - residual read from global (L1-hot row sq) instead of LDS -> out phase
//    has no xs dependency
// Math identical to validated R6 (max-free softmax + deferred normalization).

#define CB      24
#define CC      32
#define DD      16
#define THREEC  96
#define NBW     (512 * 128)
#define WPB     4
#define NPW     4                       // problems per wave
#define NBLK    (NBW / (WPB * NPW))     // 4096 blocks
#define XSS     34                      // xs row stride: even, <=2-way banks

__device__ __align__(16) float4 g_M4[2][8][CC];  // [h][e4][c] = Mt[h][c][4e4..]
__device__ __align__(16) float4 g_P4[2][8][CC];  // [h][e4][c] = Pt[h][c][4e4..]

__global__ void precompute_mp(const float* __restrict__ w_attn,
                              const float* __restrict__ w_proj)
{
    const int idx = blockIdx.x * 256 + threadIdx.x;   // 512 entries
    const int h = idx >> 8, e4 = (idx >> 5) & 7, c = idx & 31;
    float m[4], p[4];
    #pragma unroll
    for (int k = 0; k < 4; ++k) {
        const int e = 4 * e4 + k;
        float mm = 0.f, pp = 0.f;
        #pragma unroll
        for (int d = 0; d < DD; ++d) {
            const int i = DD * h + d;
            mm = fmaf(w_attn[e * THREEC + i],          w_attn[c * THREEC + CC + i], mm);
            pp = fmaf(w_attn[e * THREEC + 2 * CC + i], w_proj[i * CC + c],          pp);
        }
        m[k] = 0.25f * mm;                        // fold 1/sqrt(D)
        p[k] = pp;
    }
    g_M4[h][e4][c] = make_float4(m[0], m[1], m[2], m[3]);
    g_P4[h][e4][c] = make_float4(p[0], p[1], p[2], p[3]);
}

struct __align__(16) WaveSmem {
    float xs[CB][XSS];          // staged x rows, zero-filled past L (3264 B)
    float rks[2][CC];           // rk per head (16B-aligned halves)
    float ps[2][CC];            // UNNORMALIZED exp(score); masked slots 0
    float ys[2][CC];            // normalized p @ x per head
};                              // 4032 B -> 4 waves = 15.75 KB/block

__device__ __forceinline__ void wave_fence() {
    __asm__ volatile("s_waitcnt lgkmcnt(0)" ::: "memory");
}

__global__ __launch_bounds__(256, 8) void char_attn_kernel(
    const float* __restrict__ x,        // [B*W, 24, 32]
    const int*   __restrict__ xend,     // [B*W]
    float*       __restrict__ out)      // [B*W, 32]
{
    __shared__ WaveSmem sm[WPB];

    const int tid  = threadIdx.x;
    const int lane = tid & 63;
    const int wave = tid >> 6;
    WaveSmem& S = sm[wave];

    const int i32  = lane & 31;
    const int half = lane >> 5;

    const int sbase = __builtin_amdgcn_readfirstlane(
                          (blockIdx.x * WPB + wave) * NPW);
    const int* __restrict__ xe = xend + sbase;

    // ---- prologue: xend pipeline, x prefetch, xq s_loads for problem 0 ----
    int sq  = __builtin_amdgcn_readfirstlane(xe[0]);
    int sqn = __builtin_amdgcn_readfirstlane(xe[1]);

    float4 pf[3];
    {
        const float4* xp = (const float4*)(x + (size_t)sbase * (CB * CC));
        const int n4 = (sq + 1) * 8;            // float4s in prefix (<=192)
        #pragma unroll
        for (int i = 0; i < 3; ++i) {
            const int t = lane + 64 * i;
            pf[i] = make_float4(0.f, 0.f, 0.f, 0.f);
            if (t < n4) pf[i] = xp[t];          // coalesced 1KB/instr
        }
    }
    float4 xqv[8];                              // uniform addr -> s_load (SGPR)
    {
        const float* xq0 = x + (size_t)sbase * (CB * CC) + sq * CC;
        #pragma unroll
        for (int e = 0; e < 8; ++e) xqv[e] = *(const float4*)(xq0 + 4 * e);
    }

    #pragma unroll 1
    for (int k = 0; k < NPW; ++k) {
        const int pid = sbase + k;
        const float* __restrict__ xb = x + (size_t)pid * (CB * CC);
        const int n4 = (sq + 1) * 8;

        // ---- stage problem k (zero past prefix; keeps y-loop static) ----
        #pragma unroll
        for (int i = 0; i < 3; ++i) {
            const int t = lane + 64 * i;        // t < 192 always
            const float4 v = (t < n4) ? pf[i] : make_float4(0.f, 0.f, 0.f, 0.f);
            const int r = t >> 3, c = (t & 7) * 4;
            *(float2*)&S.xs[r][c]     = make_float2(v.x, v.y);  // 8B-aligned
            *(float2*)&S.xs[r][c + 2] = make_float2(v.z, v.w);
        }

        // ---- issue prefetch for problem k+1 (lands under k's compute) ----
        if (k + 1 < NPW) {
            const float4* xp = (const float4*)(xb + CB * CC);
            const int n4n = (sqn + 1) * 8;
            #pragma unroll
            for (int i = 0; i < 3; ++i) {
                const int t = lane + 64 * i;
                if (t < n4n) pf[i] = xp[t];     // stale lanes masked at write
            }
        }
        const int sqf = __builtin_amdgcn_readfirstlane(
                            xe[(k + 2 < NPW) ? k + 2 : NPW - 1]);

        // ---- rk (before stage fence; xqv is SGPR, M is L1-hot) ----
        {
            float a0 = 0.f, a1 = 0.f, a2 = 0.f, a3 = 0.f;
            #pragma unroll
            for (int e4 = 0; e4 < 8; ++e4) {
                const float4 mv = g_M4[half][e4][i32];  // coalesced, L1-hot
                a0 = fmaf(mv.x, xqv[e4].x, a0);
                a1 = fmaf(mv.y, xqv[e4].y, a1);
                a2 = fmaf(mv.z, xqv[e4].z, a2);
                a3 = fmaf(mv.w, xqv[e4].w, a3);
            }
            S.rks[half][i32] = (a0 + a1) + (a2 + a3);
        }
        wave_fence();                           // stage writes + rks visible

        // ---- issue xq s_loads for problem k+1 (overlap scores/y/out) ----
        float4 xqn[8];
        if (k + 1 < NPW) {
            const float* xqp = xb + CB * CC + sqn * CC;
            #pragma unroll
            for (int e = 0; e < 8; ++e) xqn[e] = *(const float4*)(xqp + 4 * e);
        }

        // ---- scores + exp (no max-subtract; s ~ N(0,1)) ----
        float rsum;
        {
            const float4* rk4 = (const float4*)&S.rks[half][0];  // b128 bcast
            float a0 = 0.f, a1 = 0.f, a2 = 0.f, a3 = 0.f;
            #pragma unroll
            for (int e4 = 0; e4 < 8; ++e4) {
                const float4 rv = rk4[e4];
                const float2 x0 = *(const float2*)&S.xs[i32][e4 * 4];     // 2-way
                const float2 x1 = *(const float2*)&S.xs[i32][e4 * 4 + 2];
                a0 = fmaf(rv.x, x0.x, a0);
                a1 = fmaf(rv.y, x0.y, a1);
                a2 = fmaf(rv.z, x1.x, a2);
                a3 = fmaf(rv.w, x1.y, a3);
            }
            const float e = (i32 <= sq) ? __expf((a0 + a1) + (a2 + a3)) : 0.f;
            S.ps[half][i32] = e;                // unnormalized; 0 for masked j
            float sum = e;
            #pragma unroll
            for (int off = 16; off >= 1; off >>= 1)
                sum += __shfl_xor(sum, off);
            rsum = __fdividef(1.f, sum);
        }
        wave_fence();                           // ps visible

        // ---- y: static 24-unroll; ps preloaded via 6 b128 broadcasts ----
        {
            float4 pr[6];
            const float4* ps4 = (const float4*)&S.ps[half][0];
            #pragma unroll
            for (int i = 0; i < 6; ++i) pr[i] = ps4[i];     // ps[0..23]
            const float* pfv = (const float*)&pr[0];
            float a0 = 0.f, a1 = 0.f;
            #pragma unroll
            for (int j = 0; j < CB; j += 2) {
                a0 = fmaf(pfv[j],     S.xs[j][i32],     a0); // conflict-free
                a1 = fmaf(pfv[j + 1], S.xs[j + 1][i32], a1);
            }
            S.ys[half][i32] = (a0 + a1) * rsum;
        }
        wave_fence();                           // ys visible

        // ---- out[c] = sum_h ys[h] . Pt[h][c][:] + residual (global, L1-hot) ----
        {
            const float4* y4 = (const float4*)&S.ys[half][0];   // b128 bcast
            float a0 = 0.f, a1 = 0.f, a2 = 0.f, a3 = 0.f;
            #pragma unroll
            for (int e4 = 0; e4 < 8; ++e4) {
                const float4 pv = g_P4[half][e4][i32];          // coalesced, L1-hot
                const float4 yv = y4[e4];
                a0 = fmaf(pv.x, yv.x, a0);
                a1 = fmaf(pv.y, yv.y, a1);
                a2 = fmaf(pv.z, yv.z, a2);
                a3 = fmaf(pv.w, yv.w, a3);
            }
            float t = (a0 + a1) + (a2 + a3);
            t += __shfl_xor(t, 32);             // combine the two heads
            const float resid = xb[sq * CC + i32];  // L1-hot (row sq prefetched)
            if (lane < CC)
                out[(size_t)pid * CC + i32] = t + resid;
        }

        // ---- advance pipelines ----
        sq = sqn; sqn = sqf;
        if (k + 1 < NPW) {
            #pragma unroll
            for (int e = 0; e < 8; ++e) xqv[e] = xqn[e];
        }
    }
}

extern "C" void kernel_launch(void* const* d_in, const int* in_sizes, int n_in,
                              void* d_out, int out_size, void* d_ws, size_t ws_size,
                              hipStream_t stream) {
    const float* x      = (const float*)d_in[0];
    const int*   xend   = (const int*)d_in[1];
    const float* w_attn = (const float*)d_in[2];
    const float* w_proj = (const float*)d_in[3];
    float* out = (float*)d_out;

    precompute_mp<<<dim3(2), dim3(256), 0, stream>>>(w_attn, w_proj);
    char_attn_kernel<<<dim3(NBLK), dim3(WPB * 64), 0, stream>>>(
        x, xend, out);
}

// Round 8
// 289.665 us; speedup vs baseline: 1.1237x; 1.0468x over previous
//
#include <hip/hip_runtime.h>

// CharAttention round-8: CONSOLIDATION on the measured-best R3 skeleton.
// Ledger after 7 rounds: hot compute pass = 30us (NREP-measured), first-pass
// overhead ~55us resists persistence (R5), deep prefetch (R7), and block-count
// reduction -> keep the simplest structure (1 problem/wave, work ~ L, 3
// fences) and fold in only validated micro-wins:
//  - float4 staging, DYNAMIC trip (avg 1.6 iters vs R3's 3.2 float2 iters):
//    halves staging VMEM instrs and serial load->ds_write latencies. Rows
//    past L stay garbage: y-loop bounds at L, score lanes i32>sq masked.
//  - max-free softmax (s ~ N(0,1), validated 3x) + deferred normalization:
//    removes the 5-shuffle max chain; 1/sum folded into the ys write.
//  - WPB=8 (512-thread blocks, 8192 blocks, 4 blocks/CU, 32 waves/CU): pure
//    block-granularity probe, zero structural change.
//  - folded weights M = 0.25*Wq Wk^T, P = Wv Wproj per head (precomputed,
//    stored [h][e4][c] float4 -> coalesced, L1-hot).
// One wave per problem, 3 lgkmcnt fences, all wave-local, no __syncthreads.

#define CB      24
#define CC      32
#define DD      16
#define THREEC  96
#define NBW     (512 * 128)
#define WPB     8
#define NBLK    (NBW / WPB)             // 8192 blocks
#define XSS     34                      // xs row stride: even, <=2-way banks

__device__ __align__(16) float4 g_M4[2][8][CC];  // [h][e4][c] = Mt[h][c][4e4..]
__device__ __align__(16) float4 g_P4[2][8][CC];  // [h][e4][c] = Pt[h][c][4e4..]

__global__ void precompute_mp(const float* __restrict__ w_attn,
                              const float* __restrict__ w_proj)
{
    const int idx = blockIdx.x * 256 + threadIdx.x;   // 512 entries
    const int h = idx >> 8, e4 = (idx >> 5) & 7, c = idx & 31;
    float m[4], p[4];
    #pragma unroll
    for (int k = 0; k < 4; ++k) {
        const int e = 4 * e4 + k;
        float mm = 0.f, pp = 0.f;
        #pragma unroll
        for (int d = 0; d < DD; ++d) {
            const int i = DD * h + d;
            mm = fmaf(w_attn[e * THREEC + i],          w_attn[c * THREEC + CC + i], mm);
            pp = fmaf(w_attn[e * THREEC + 2 * CC + i], w_proj[i * CC + c],          pp);
        }
        m[k] = 0.25f * mm;                        // fold 1/sqrt(D)
        p[k] = pp;
    }
    g_M4[h][e4][c] = make_float4(m[0], m[1], m[2], m[3]);
    g_P4[h][e4][c] = make_float4(p[0], p[1], p[2], p[3]);
}

struct __align__(16) WaveSmem {
    float xs[CB][XSS];          // staged x rows 0..sq (3264 B); rest garbage
    float rks[2][CC];           // rk per head (16B-aligned halves)
    float ps[2][CC];            // UNNORMALIZED exp(score); masked slots 0
    float ys[2][CC];            // normalized p @ x per head
};                              // 4032 B -> 8 waves = 31.5 KB/block

__device__ __forceinline__ void wave_fence() {
    __asm__ volatile("s_waitcnt lgkmcnt(0)" ::: "memory");
}

__global__ __launch_bounds__(512, 8) void char_attn_kernel(
    const float* __restrict__ x,        // [B*W, 24, 32]
    const int*   __restrict__ xend,     // [B*W]
    float*       __restrict__ out)      // [B*W, 32]
{
    __shared__ WaveSmem sm[WPB];

    const int tid  = threadIdx.x;
    const int lane = tid & 63;
    const int wave = tid >> 6;
    WaveSmem& S = sm[wave];

    const int i32  = lane & 31;
    const int half = lane >> 5;

    // Wave-uniform scalars -> SGPR; derived addresses stay on the scalar path.
    const int sbid = __builtin_amdgcn_readfirstlane(blockIdx.x * WPB + wave);
    const int sq   = __builtin_amdgcn_readfirstlane(xend[sbid]);
    const int L    = sq + 1;

    const float* __restrict__ xb = x + (size_t)sbid * (CB * CC);
    const float* __restrict__ xq = xb + sq * CC;    // uniform addr -> s_load

    // xq via SMEM pipe, issued first so latency overlaps staging
    float4 xqv[8];
    #pragma unroll
    for (int e = 0; e < 8; ++e) xqv[e] = *(const float4*)(xq + 4 * e);

    // ---- stage x rows 0..sq (float4, dynamic wave-uniform trip ~1.6) ----
    {
        const float4* xb4 = (const float4*)xb;
        const int n4 = L * (CC / 4);            // <= 192
        for (int t = lane; t < n4; t += 64) {
            const float4 v = xb4[t];            // coalesced 1KB/instr
            const int r = t >> 3, c = (t & 7) * 4;
            *(float2*)&S.xs[r][c]     = make_float2(v.x, v.y);  // 8B-aligned
            *(float2*)&S.xs[r][c + 2] = make_float2(v.z, v.w);
        }
    }

    // ---- rk (before stage fence: no LDS reads; M coalesced L1-hot) ----
    {
        float a0 = 0.f, a1 = 0.f, a2 = 0.f, a3 = 0.f;
        #pragma unroll
        for (int e4 = 0; e4 < 8; ++e4) {
            const float4 mv = g_M4[half][e4][i32];
            a0 = fmaf(mv.x, xqv[e4].x, a0);
            a1 = fmaf(mv.y, xqv[e4].y, a1);
            a2 = fmaf(mv.z, xqv[e4].z, a2);
            a3 = fmaf(mv.w, xqv[e4].w, a3);
        }
        S.rks[half][i32] = (a0 + a1) + (a2 + a3);
    }
    wave_fence();                               // stage writes + rks visible

    // ---- scores + exp (no max-subtract; s ~ N(0,1)) + deferred norm ----
    float rsum;
    {
        const float4* rk4 = (const float4*)&S.rks[half][0];  // b128 broadcast
        float a0 = 0.f, a1 = 0.f, a2 = 0.f, a3 = 0.f;
        #pragma unroll
        for (int e4 = 0; e4 < 8; ++e4) {
            const float4 rv = rk4[e4];
            const float2 x0 = *(const float2*)&S.xs[i32][e4 * 4];     // 2-way max
            const float2 x1 = *(const float2*)&S.xs[i32][e4 * 4 + 2];
            a0 = fmaf(rv.x, x0.x, a0);
            a1 = fmaf(rv.y, x0.y, a1);
            a2 = fmaf(rv.z, x1.x, a2);
            a3 = fmaf(rv.w, x1.y, a3);
        }
        const float e = (i32 <= sq) ? __expf((a0 + a1) + (a2 + a3)) : 0.f;
        S.ps[half][i32] = e;                    // unnormalized; 0 for masked j
        float sum = e;
        #pragma unroll
        for (int off = 16; off >= 1; off >>= 1)
            sum += __shfl_xor(sum, off);
        rsum = __fdividef(1.f, sum);
    }
    wave_fence();                               // ps visible

    // ---- y: ys[h][c] = (sum_j e[h][j] xs[j][c]) * rsum (trip ~ L) ----
    {
        float a0 = 0.f, a1 = 0.f;
        int j = 0;
        for (; j + 1 < L; j += 2) {
            const float2 p2 = *(const float2*)&S.ps[half][j];   // b64 broadcast
            a0 = fmaf(p2.x, S.xs[j][i32],     a0);              // conflict-free
            a1 = fmaf(p2.y, S.xs[j + 1][i32], a1);
        }
        if (j < L)
            a0 = fmaf(S.ps[half][j], S.xs[j][i32], a0);
        S.ys[half][i32] = (a0 + a1) * rsum;
    }
    wave_fence();                               // ys visible

    // ---- out[c] = sum_h ys[h] . Pt[h][c][:] + residual ----
    {
        const float4* y4 = (const float4*)&S.ys[half][0];       // b128 broadcast
        float a0 = 0.f, a1 = 0.f, a2 = 0.f, a3 = 0.f;
        #pragma unroll
        for (int e4 = 0; e4 < 8; ++e4) {
            const float4 pv = g_P4[half][e4][i32];              // coalesced, L1-hot
            const float4 yv = y4[e4];
            a0 = fmaf(pv.x, yv.x, a0);
            a1 = fmaf(pv.y, yv.y, a1);
            a2 = fmaf(pv.z, yv.z, a2);
            a3 = fmaf(pv.w, yv.w, a3);
        }
        float t = (a0 + a1) + (a2 + a3);
        t += __shfl_xor(t, 32);                 // combine the two heads
        if (lane < CC)
            out[(size_t)sbid * CC + i32] = t + S.xs[sq][i32];   // residual (LDS)
    }
}

extern "C" void kernel_launch(void* const* d_in, const int* in_sizes, int n_in,
                              void* d_out, int out_size, void* d_ws, size_t ws_size,
                              hipStream_t stream) {
    const float* x      = (const float*)d_in[0];
    const int*   xend   = (const int*)d_in[1];
    const float* w_attn = (const float*)d_in[2];
    const float* w_proj = (const float*)d_in[3];
    float* out = (float*)d_out;

    precompute_mp<<<dim3(2), dim3(256), 0, stream>>>(w_attn, w_proj);
    char_attn_kernel<<<dim3(NBLK), dim3(WPB * 64), 0, stream>>>(
        x, xend, out);
}

// Round 9
// 287.599 us; speedup vs baseline: 1.1318x; 1.0072x over previous
//
#include <hip/hip_runtime.h>

// CharAttention round-9: R8 skeleton (measured best, 289.7us) + ONE change:
// UNCONDITIONAL static staging. All 24 rows of x exist for every problem
// (only the use is prefix-limited), so staging needs no sq: exactly 3 b128
// loads + 6 b64 LDS writes per lane, no predicates. The staging VMEM now
// issues at cycle 0 IN PARALLEL with the xend s_load, removing the
// xend->VMEM serialization (~300-900cy) from every problem's cold chain.
// Rows past sq are real finite data: y bounds at L, score lanes i32>sq are
// masked, residual row sq valid. Everything else identical to R8:
//  - folded weights M=0.25*Wq Wk^T, P=Wv Wproj ([h][e4][c] float4, L1-hot)
//  - xq via s_load (SMEM pipe) overlapping staging
//  - rk before the single stage fence; 3 lgkmcnt fences total
//  - max-free softmax + deferred normalization (validated, absmax 0.0078)
//  - y-loop dynamic (work ~ L), WPB=8 (512 threads), 8192 blocks, 32 waves/CU
// Model: hot pass DS-bound on xs reads (~250cy/wave -> 27us, matches NREP);
// this round attacks the ~50us cold latency component.

#define CB      24
#define CC      32
#define DD      16
#define THREEC  96
#define NBW     (512 * 128)
#define WPB     8
#define NBLK    (NBW / WPB)             // 8192 blocks
#define XSS     34                      // xs row stride: even, <=2-way banks

__device__ __align__(16) float4 g_M4[2][8][CC];  // [h][e4][c] = Mt[h][c][4e4..]
__device__ __align__(16) float4 g_P4[2][8][CC];  // [h][e4][c] = Pt[h][c][4e4..]

__global__ void precompute_mp(const float* __restrict__ w_attn,
                              const float* __restrict__ w_proj)
{
    const int idx = blockIdx.x * 256 + threadIdx.x;   // 512 entries
    const int h = idx >> 8, e4 = (idx >> 5) & 7, c = idx & 31;
    float m[4], p[4];
    #pragma unroll
    for (int k = 0; k < 4; ++k) {
        const int e = 4 * e4 + k;
        float mm = 0.f, pp = 0.f;
        #pragma unroll
        for (int d = 0; d < DD; ++d) {
            const int i = DD * h + d;
            mm = fmaf(w_attn[e * THREEC + i],          w_attn[c * THREEC + CC + i], mm);
            pp = fmaf(w_attn[e * THREEC + 2 * CC + i], w_proj[i * CC + c],          pp);
        }
        m[k] = 0.25f * mm;                        // fold 1/sqrt(D)
        p[k] = pp;
    }
    g_M4[h][e4][c] = make_float4(m[0], m[1], m[2], m[3]);
    g_P4[h][e4][c] = make_float4(p[0], p[1], p[2], p[3]);
}

struct __align__(16) WaveSmem {
    float xs[CB][XSS];          // ALL 24 x rows (3264 B)
    float rks[2][CC];           // rk per head (16B-aligned halves)
    float ps[2][CC];            // UNNORMALIZED exp(score); masked slots 0
    float ys[2][CC];            // normalized p @ x per head
};                              // 4032 B -> 8 waves = 31.5 KB/block

__device__ __forceinline__ void wave_fence() {
    __asm__ volatile("s_waitcnt lgkmcnt(0)" ::: "memory");
}

__global__ __launch_bounds__(512, 8) void char_attn_kernel(
    const float* __restrict__ x,        // [B*W, 24, 32]
    const int*   __restrict__ xend,     // [B*W]
    float*       __restrict__ out)      // [B*W, 32]
{
    __shared__ WaveSmem sm[WPB];

    const int tid  = threadIdx.x;
    const int lane = tid & 63;
    const int wave = tid >> 6;
    WaveSmem& S = sm[wave];

    const int i32  = lane & 31;
    const int half = lane >> 5;

    const int sbid = __builtin_amdgcn_readfirstlane(blockIdx.x * WPB + wave);
    const float* __restrict__ xb = x + (size_t)sbid * (CB * CC);

    // ---- stage ALL 24 rows: 3 unconditional b128 loads, issued at cycle 0,
    //      independent of xend (the dependency this round removes) ----
    float4 st0, st1, st2;
    {
        const float4* xb4 = (const float4*)xb;  // 192 float4s total
        st0 = xb4[lane];
        st1 = xb4[lane + 64];
        st2 = xb4[lane + 128];
    }

    // xend + xq on the scalar pipe, overlapping the staging loads
    const int sq = __builtin_amdgcn_readfirstlane(xend[sbid]);
    const int L  = sq + 1;
    const float* __restrict__ xq = xb + sq * CC;    // uniform addr -> s_load
    float4 xqv[8];
    #pragma unroll
    for (int e = 0; e < 8; ++e) xqv[e] = *(const float4*)(xq + 4 * e);

    // LDS writes (compiler inserts the vmcnt waits per value)
    {
        const int r0 = lane >> 3,         c0 = (lane & 7) * 4;
        const int r1 = (lane + 64) >> 3,  c1 = c0;   // +64 preserves (t&7)
        const int r2 = (lane + 128) >> 3, c2 = c0;
        *(float2*)&S.xs[r0][c0]     = make_float2(st0.x, st0.y);
        *(float2*)&S.xs[r0][c0 + 2] = make_float2(st0.z, st0.w);
        *(float2*)&S.xs[r1][c1]     = make_float2(st1.x, st1.y);
        *(float2*)&S.xs[r1][c1 + 2] = make_float2(st1.z, st1.w);
        *(float2*)&S.xs[r2][c2]     = make_float2(st2.x, st2.y);
        *(float2*)&S.xs[r2][c2 + 2] = make_float2(st2.z, st2.w);
    }

    // ---- rk (before stage fence: no LDS reads; M coalesced L1-hot) ----
    {
        float a0 = 0.f, a1 = 0.f, a2 = 0.f, a3 = 0.f;
        #pragma unroll
        for (int e4 = 0; e4 < 8; ++e4) {
            const float4 mv = g_M4[half][e4][i32];
            a0 = fmaf(mv.x, xqv[e4].x, a0);
            a1 = fmaf(mv.y, xqv[e4].y, a1);
            a2 = fmaf(mv.z, xqv[e4].z, a2);
            a3 = fmaf(mv.w, xqv[e4].w, a3);
        }
        S.rks[half][i32] = (a0 + a1) + (a2 + a3);
    }
    wave_fence();                               // stage writes + rks visible

    // ---- scores + exp (no max-subtract; s ~ N(0,1)) + deferred norm ----
    float rsum;
    {
        const float4* rk4 = (const float4*)&S.rks[half][0];  // uniform broadcast
        float a0 = 0.f, a1 = 0.f, a2 = 0.f, a3 = 0.f;
        #pragma unroll
        for (int e4 = 0; e4 < 8; ++e4) {
            const float4 rv = rk4[e4];
            const float2 x0 = *(const float2*)&S.xs[i32][e4 * 4];     // 2-way max
            const float2 x1 = *(const float2*)&S.xs[i32][e4 * 4 + 2];
            a0 = fmaf(rv.x, x0.x, a0);
            a1 = fmaf(rv.y, x0.y, a1);
            a2 = fmaf(rv.z, x1.x, a2);
            a3 = fmaf(rv.w, x1.y, a3);
        }
        const float e = (i32 <= sq) ? __expf((a0 + a1) + (a2 + a3)) : 0.f;
        S.ps[half][i32] = e;                    // unnormalized; 0 for masked j
        float sum = e;
        #pragma unroll
        for (int off = 16; off >= 1; off >>= 1)
            sum += __shfl_xor(sum, off);
        rsum = __fdividef(1.f, sum);
    }
    wave_fence();                               // ps visible

    // ---- y: ys[h][c] = (sum_j e[h][j] xs[j][c]) * rsum (trip ~ L) ----
    {
        float a0 = 0.f, a1 = 0.f;
        int j = 0;
        for (; j + 1 < L; j += 2) {
            const float2 p2 = *(const float2*)&S.ps[half][j];   // uniform bcast
            a0 = fmaf(p2.x, S.xs[j][i32],     a0);              // conflict-free
            a1 = fmaf(p2.y, S.xs[j + 1][i32], a1);
        }
        if (j < L)
            a0 = fmaf(S.ps[half][j], S.xs[j][i32], a0);
        S.ys[half][i32] = (a0 + a1) * rsum;
    }
    wave_fence();                               // ys visible

    // ---- out[c] = sum_h ys[h] . Pt[h][c][:] + residual ----
    {
        const float4* y4 = (const float4*)&S.ys[half][0];       // uniform bcast
        float a0 = 0.f, a1 = 0.f, a2 = 0.f, a3 = 0.f;
        #pragma unroll
        for (int e4 = 0; e4 < 8; ++e4) {
            const float4 pv = g_P4[half][e4][i32];              // coalesced, L1-hot
            const float4 yv = y4[e4];
            a0 = fmaf(pv.x, yv.x, a0);
            a1 = fmaf(pv.y, yv.y, a1);
            a2 = fmaf(pv.z, yv.z, a2);
            a3 = fmaf(pv.w, yv.w, a3);
        }
        float t = (a0 + a1) + (a2 + a3);
        t += __shfl_xor(t, 32);                 // combine the two heads
        if (lane < CC)
            out[(size_t)sbid * CC + i32] = t + S.xs[sq][i32];   // residual (LDS)
    }
}

extern "C" void kernel_launch(void* const* d_in, const int* in_sizes, int n_in,
                              void* d_out, int out_size, void* d_ws, size_t ws_size,
                              hipStream_t stream) {
    const float* x      = (const float*)d_in[0];
    const int*   xend   = (const int*)d_in[1];
    const float* w_attn = (const float*)d_in[2];
    const float* w_proj = (const float*)d_in[3];
    float* out = (float*)d_out;

    precompute_mp<<<dim3(2), dim3(256), 0, stream>>>(w_attn, w_proj);
    char_attn_kernel<<<dim3(NBLK), dim3(WPB * 64), 0, stream>>>(
        x, xend, out);
}